// Round 19
// baseline (309.940 us; speedup 1.0000x reference)
//
#include <hip/hip_runtime.h>
#include <hip/hip_bf16.h>
#include <stdint.h>

typedef __bf16 bf16_t;
typedef __bf16 bf16x8 __attribute__((ext_vector_type(8)));
typedef float f32x4 __attribute__((ext_vector_type(4)));
typedef float f32x16 __attribute__((ext_vector_type(16)));

#define S_TOK 8192
#define DIM   1280
#define NH    16
#define HD    80
#define LSEQ  1024
#define N_QKV 3840

// q/k columns are stored PAIR-INTERLEAVED per head: col j (even) = orig d=j/2,
// col j (odd) = orig d=j/2+40. QK^T is invariant (q,k share the permutation);
// V region (n>=2560) is identity. qk_perm maps stored col -> original col.
__device__ __forceinline__ int qk_perm(int n) {
  if (n >= 2560) return n;
  int base = (n / 80) * 80, j = n - base;
  return base + ((j & 1) ? (j >> 1) + 40 : (j >> 1));
}

// async global->LDS, 16B per lane; lds dest is wave-uniform base + lane*16
__device__ __forceinline__ void gload16(const bf16_t* g, void* l) {
  __builtin_amdgcn_global_load_lds(
      (__attribute__((address_space(1))) uint32_t*)g,
      (__attribute__((address_space(3))) uint32_t*)l, 16, 0, 0);
}

// ---------------- fp32 -> bf16 convert (hidden_states) ----------------
__global__ __launch_bounds__(256) void k_conv_bf16(const float* __restrict__ in,
                                                   bf16_t* __restrict__ out) {
  int g = blockIdx.x * 256 + threadIdx.x;
  const float4* p = reinterpret_cast<const float4*>(in) + (size_t)g * 2;
  float4 v0 = p[0], v1 = p[1];
  bf16x8 o;
  o[0] = (bf16_t)v0.x; o[1] = (bf16_t)v0.y; o[2] = (bf16_t)v0.z; o[3] = (bf16_t)v0.w;
  o[4] = (bf16_t)v1.x; o[5] = (bf16_t)v1.y; o[6] = (bf16_t)v1.z; o[7] = (bf16_t)v1.w;
  *reinterpret_cast<bf16x8*>(out + (size_t)g * 8) = o;
}

// ---------------- W [K][N] fp32 -> Wt [N][K] bf16 ----------------
__global__ __launch_bounds__(256) void k_transpose_bf16(const float* __restrict__ W,
                                                        bf16_t* __restrict__ Wt,
                                                        int K, int N) {
  __shared__ float tile[32][33];
  int n0 = blockIdx.x * 32, k0 = blockIdx.y * 32;
  int tx = threadIdx.x, ty = threadIdx.y;
#pragma unroll
  for (int j = 0; j < 32; j += 8)
    tile[ty + j][tx] = W[(size_t)(k0 + ty + j) * N + n0 + tx];
  __syncthreads();
#pragma unroll
  for (int j = 0; j < 32; j += 8)
    Wt[(size_t)(n0 + ty + j) * K + k0 + tx] = (bf16_t)tile[tx][ty + j];
}

// ---------------- GEMM v8: 256x256, BK=64, 2-phase dbuf + fused RoPE + LDS writeback ----------------
// ROPE path epilogue: cos/sin staged to LDS (coalesced), then C written back
// through a [64][264] LDS tile in 4 chunks -> 16B/lane full-line global stores
// (kills the partial-line RMW that cost ~120MB of excess L2/HBM traffic).
// fp32 path keeps direct stores (16 lanes x 4B = full 64B line already).
// Race-free 2-phase K-loop: all waits vmcnt(0), one barrier per K-tile.
template <bool OUT_BF16, bool ROPE>
__global__ __launch_bounds__(512, 2) void k_gemm8(const bf16_t* __restrict__ A,
                                                  const bf16_t* __restrict__ Bt,
                                                  const float* __restrict__ bias,
                                                  void* __restrict__ Cout,
                                                  int N,
                                                  const float* __restrict__ cosT,
                                                  const float* __restrict__ sinT) {
  constexpr int K = 1280;
  constexpr int NT = K / 64;                     // 20 K-tiles
  const float QS = 0.11180339887498949f * 1.4426950408889634f;
  __shared__ __align__(16) char smem[131072];    // [2][A 32KB | B 32KB]
  const int nb = N >> 8;
  const int cpx = (int)gridDim.x >> 3;           // grid % 8 == 0
  const int wg = ((int)blockIdx.x & 7) * cpx + ((int)blockIdx.x >> 3);
  const int bm = wg / nb, bn = wg % nb;
  const int tid = threadIdx.x, lane = tid & 63, w = tid >> 6;
  const int wm = w >> 2, wn = w & 3;             // 2 x 4 wave grid
  const int l15 = lane & 15, lg = lane >> 4;

  const bf16_t* Ab = A + (size_t)(bm * 256) * K;

  const int srow = w * 8 + (lane >> 3);
  const int scol = ((lane & 7) ^ (lane >> 3)) * 8;   // inverse-swizzled source chunk

  // B source rows (permuted for the q/k-interleaved layout), precomputed
  int srowB[4];
#pragma unroll
  for (int g = 0; g < 4; ++g) {
    int n = bn * 256 + g * 64 + srow;
    srowB[g] = ROPE ? qk_perm(n) : n;
  }

  // bias preload (permuted for ROPE); all waits below are vmcnt(0), no hazard
  float bv4[4];
#pragma unroll
  for (int nf = 0; nf < 4; ++nf) {
    int col = bn * 256 + wn * 64 + nf * 16 + l15;
    bv4[nf] = bias[ROPE ? qk_perm(col) : col];
  }
  asm volatile("" :: "v"(bv4[0]), "v"(bv4[1]), "v"(bv4[2]), "v"(bv4[3]) : "memory");

  char* const sm = smem;
  auto stageA = [&](int buf, int g, int k0) {
    gload16(Ab + (size_t)(g * 64 + srow) * K + k0 + scol,
            sm + buf * 65536 + g * 8192 + w * 1024);
  };
  auto stageB = [&](int buf, int g, int k0) {
    gload16(Bt + (size_t)srowB[g] * K + k0 + scol,
            sm + buf * 65536 + 32768 + g * 8192 + w * 1024);
  };

  f32x4 acc[8][4];
#pragma unroll
  for (int i = 0; i < 8; ++i)
#pragma unroll
    for (int j = 0; j < 4; ++j) acc[i][j] = (f32x4){0.f, 0.f, 0.f, 0.f};

  // prologue: stage tile 0, wait, barrier
#pragma unroll
  for (int g = 0; g < 4; ++g) { stageA(0, g, 0); stageB(0, g, 0); }
  asm volatile("s_waitcnt vmcnt(0)\n\ts_barrier" ::: "memory");

#pragma unroll 1
  for (int T = 0; T < NT; ++T) {
    const int buf = T & 1, nbuf = buf ^ 1;
    const int k1 = (T + 1) * 64;
    if (T + 1 < NT) {
      // safe: nbuf last read at iter T-1, sealed by that iter's vmcnt(0)+barrier
#pragma unroll
      for (int g = 0; g < 4; ++g) { stageA(nbuf, g, k1); stageB(nbuf, g, k1); }
    }
    const char* Abase = sm + buf * 65536;
    const char* Bbase = Abase + 32768;
#pragma unroll
    for (int kk = 0; kk < 2; ++kk) {
      const int cb = kk * 64 + lg * 16;
      bf16x8 bfv[4];
#pragma unroll
      for (int nf = 0; nf < 4; ++nf) {
        const int row = wn * 64 + nf * 16 + l15;
        bfv[nf] = *reinterpret_cast<const bf16x8*>(Bbase + row * 128 + (cb ^ ((row & 7) << 4)));
      }
#pragma unroll
      for (int mg = 0; mg < 2; ++mg) {
        bf16x8 af[4];
#pragma unroll
        for (int mf = 0; mf < 4; ++mf) {
          const int row = wm * 128 + mg * 64 + mf * 16 + l15;
          af[mf] = *reinterpret_cast<const bf16x8*>(Abase + row * 128 + (cb ^ ((row & 7) << 4)));
        }
        __builtin_amdgcn_s_setprio(1);
#pragma unroll
        for (int mf = 0; mf < 4; ++mf)
#pragma unroll
          for (int nf = 0; nf < 4; ++nf)
            acc[mg * 4 + mf][nf] =
                __builtin_amdgcn_mfma_f32_16x16x32_bf16(af[mf], bfv[nf], acc[mg * 4 + mf][nf], 0, 0, 0);
        __builtin_amdgcn_s_setprio(0);
      }
    }
    if (T + 1 < NT) {
      // T+1's loads (in flight during compute) land; all waves done reading buf
      asm volatile("s_waitcnt vmcnt(0)\n\ts_barrier" ::: "memory");
    }
  }

  const int rg = lg << 2;

  if constexpr (OUT_BF16 && ROPE) {
    // ---- stage cos/sin [256 rows][40 pi] into dead LDS (coalesced) ----
    float* ldsC = reinterpret_cast<float*>(sm);            // [256][44] padded
    float* ldsS = reinterpret_cast<float*>(sm + 45056);    // [256][44]
    bf16_t* Cs  = reinterpret_cast<bf16_t*>(sm + 90112);   // [64][264] bf16 (33792 B)
    __syncthreads();                                       // all K-loop LDS reads done
#pragma unroll
    for (int i = 0; i < 5; ++i) {
      int c = tid + i * 512;                               // 2560 float4 per table
      int row = c / 10, q4 = c - row * 10;
      float4 vc = *reinterpret_cast<const float4*>(cosT + (size_t)(bm * 256 + row) * 80 + q4 * 4);
      float4 vs = *reinterpret_cast<const float4*>(sinT + (size_t)(bm * 256 + row) * 80 + q4 * 4);
      *reinterpret_cast<float4*>(ldsC + row * 44 + q4 * 4) = vc;
      *reinterpret_cast<float4*>(ldsS + row * 44 + q4 * 4) = vs;
    }
    __syncthreads();

    // ---- 4 chunks of 64 local rows: rope -> LDS tile -> coalesced writeback ----
#pragma unroll 1
    for (int cchunk = 0; cchunk < 4; ++cchunk) {
#pragma unroll
      for (int mh = 0; mh < 2; ++mh) {
        const int m8 = cchunk * 2 + mh;
#pragma unroll
        for (int nf = 0; nf < 4; ++nf) {
          const int col = wn * 64 + nf * 16 + l15;
          const int gcol = bn * 256 + col;
          const bool isqk = gcol < 2560;
          const bool isq  = gcol < 1280;
          const int pi = (gcol % 80) >> 1;
          const float sgn = (l15 & 1) ? 1.f : -1.f;
          const float bv = bv4[nf];
#pragma unroll
          for (int r = 0; r < 4; ++r) {
            const int brow = wm * 128 + m8 * 16 + rg + r;   // block row 0..255
            float v = acc[m8][nf][r] + bv;
            if (isqk) {
              float other = __shfl_xor(v, 1);
              float c = ldsC[brow * 44 + pi];
              float s = ldsS[brow * 44 + pi];
              v = v * c + sgn * other * s;                  // even: xc-ys ; odd: yc+xs
              if (isq) v *= QS;
            }
            const int lr = wm * 32 + mh * 16 + rg + r;      // chunk-local row 0..63
            Cs[lr * 264 + col] = (bf16_t)v;
          }
        }
      }
      __syncthreads();
      // readback: 64 rows x 256 cols bf16 -> 16B/lane coalesced global stores
#pragma unroll
      for (int i = 0; i < 4; ++i) {
        int id = tid + i * 512;
        int lr = id >> 5, ch = id & 31;
        uint4 vv = *reinterpret_cast<const uint4*>(Cs + lr * 264 + ch * 8);
        int grow = bm * 256 + (lr >> 5) * 128 + cchunk * 32 + (lr & 31);
        *reinterpret_cast<uint4*>(reinterpret_cast<bf16_t*>(Cout) + (size_t)grow * N + bn * 256 + ch * 8) = vv;
      }
      __syncthreads();
    }
  } else {
    // fp32 path: 16 lanes x 4B = full 64B line, direct stores are fine
#pragma unroll
    for (int nf = 0; nf < 4; ++nf) {
      const int col = bn * 256 + wn * 64 + nf * 16 + l15;
      const float bv = bv4[nf];
#pragma unroll
      for (int m8 = 0; m8 < 8; ++m8) {
        const int row0 = bm * 256 + wm * 128 + m8 * 16 + rg;
#pragma unroll
        for (int r = 0; r < 4; ++r) {
          float v = acc[m8][nf][r] + bv;
          if (OUT_BF16)
            reinterpret_cast<bf16_t*>(Cout)[(size_t)(row0 + r) * N + col] = (bf16_t)v;
          else
            reinterpret_cast<float*>(Cout)[(size_t)(row0 + r) * N + col] = v;
        }
      }
    }
  }
}

// ---------------- V transpose+permute: vtg[seg][h][d][kv'] = V[seg][swap23(kv')][h][d] ----------------
__global__ __launch_bounds__(256) void k_vtrans(const bf16_t* __restrict__ qkv,
                                                bf16_t* __restrict__ vtg) {
  __shared__ bf16_t T[64][88];
  int sh = blockIdx.x >> 4;            // seg*16 + h
  int kt = blockIdx.x & 15;
  int seg = sh >> 4, h = sh & 15;
  int kv0 = kt * 64;
  int tid = threadIdx.x;
#pragma unroll
  for (int i = 0; i < 3; ++i) {
    int c = tid + i * 256;
    if (c < 640) {
      int r = c / 10, ch = c - r * 10;
      *reinterpret_cast<uint4*>(&T[r][ch * 8]) =
        *reinterpret_cast<const uint4*>(qkv + (size_t)(seg * 1024 + kv0 + r) * N_QKV + 2 * DIM + h * 80 + ch * 8);
    }
  }
  __syncthreads();
#pragma unroll
  for (int i = 0; i < 3; ++i) {
    int c = tid + i * 256;
    if (c < 640) {
      int d = c >> 3, co = c & 7;
      bf16x8 o;
#pragma unroll
      for (int j = 0; j < 8; ++j) {
        int kp = co * 8 + j;
        int kv = (kp & ~12) | (((kp >> 2) & 1) << 3) | (((kp >> 3) & 1) << 2);  // swap bits 2,3
        o[j] = T[kv][d];
      }
      *reinterpret_cast<bf16x8*>(vtg + ((size_t)(sh * 80 + d)) * 1024 + kv0 + co * 8) = o;
    }
  }
}

// ---------------- flash attention v7: lagged-PV pipeline (QK(t) || PV(t-1) || SM) ----------------
// (byte-identical to rounds 11/14/16/18 — green at ~100 µs)
__global__ __launch_bounds__(512, 2) void k_attn2(const bf16_t* __restrict__ qkv,
                                                  const bf16_t* __restrict__ vtg,
                                                  bf16_t* __restrict__ outp) {
  __shared__ __align__(16) char smem[69632];
  bf16_t* KsB = (bf16_t*)smem;                 // 2 x [64][128]  (8192 elems per buf)
  bf16_t* VsB = (bf16_t*)(smem + 32768);       // 3 x [96][64]   (6144 elems per buf)

  const int bid = blockIdx.x;
  const int seg = bid & 7, qt = (bid >> 3) & 3, h = bid >> 5;
  const int tid = threadIdx.x, lane = tid & 63, w = tid >> 6;
  const int l31 = lane & 31, hi = lane >> 5;
  const int sw = l31 & 7;                      // row-XOR key (rows l31+32k share it)
  const int q0 = seg * 1024 + qt * 256;

  const bf16_t* kbase = qkv + ((size_t)seg * 1024) * N_QKV + DIM + h * 80;
  const bf16_t* vbase = vtg + ((size_t)(seg * 16 + h) * 80) * 1024;

  bf16x8 qf[5];
  {
    const bf16_t* qp = qkv + (size_t)(q0 + w * 32 + l31) * N_QKV + h * 80 + hi * 8;
#pragma unroll
    for (int ks = 0; ks < 5; ++ks) qf[ks] = *reinterpret_cast<const bf16x8*>(qp + ks * 16);
  }

  const uint4 ones4 = {0x3F803F80u, 0x3F803F80u, 0x3F803F80u, 0x3F803F80u};  // bf16 1.0 x8
  uint4 kreg[2], vreg[2];
  auto issue = [&](int kv0) {
#pragma unroll
    for (int i = 0; i < 2; ++i) {
      int c = tid + i * 512;
      if (c < 640) {
        int r = c / 10, ch = c - r * 10;
        kreg[i] = *reinterpret_cast<const uint4*>(kbase + (size_t)(kv0 + r) * N_QKV + ch * 8);
      }
    }
#pragma unroll
    for (int i = 0; i < 2; ++i) {
      int c = tid + i * 512;
      if (c < 768) {
        int d = c >> 3, ch = c & 7;
        uint4 v = {0u, 0u, 0u, 0u};
        if (d < 80) v = *reinterpret_cast<const uint4*>(vbase + (size_t)d * 1024 + kv0 + ch * 8);
        else if (d == 80) v = ones4;           // ones row -> o2 row 80 = sum(P)
        vreg[i] = v;
      }
    }
  };
  auto commit = [&](int kb, int vb) {
    bf16_t* Kb = KsB + kb * 8192;
    bf16_t* Vb = VsB + vb * 6144;
#pragma unroll
    for (int i = 0; i < 2; ++i) {
      int c = tid + i * 512;
      if (c < 640) {
        int r = c / 10, ch = c - r * 10;
        *reinterpret_cast<uint4*>(Kb + r * 128 + ((ch ^ (r & 7)) << 3)) = kreg[i];
      }
    }
#pragma unroll
    for (int i = 0; i < 2; ++i) {
      int c = tid + i * 512;
      if (c < 768) {
        int d = c >> 3, ch = c & 7;
        *reinterpret_cast<uint4*>(Vb + d * 64 + ((ch ^ (d & 7)) << 3)) = vreg[i];
      }
    }
  };

  f32x16 o0, o1, o2;
#pragma unroll
  for (int r = 0; r < 16; ++r) { o0[r] = 0.f; o1[r] = 0.f; o2[r] = 0.f; }
  float mrun = -1e30f;
  f32x16 st0, st1;
  bf16x8 pb[4];

  auto qk = [&](int kb) {
#pragma unroll
    for (int r = 0; r < 16; ++r) { st0[r] = 0.f; st1[r] = 0.f; }
    const bf16_t* Kb = KsB + kb * 8192;
    __builtin_amdgcn_s_setprio(1);
#pragma unroll
    for (int ks = 0; ks < 5; ++ks) {
      const int so = (((ks << 1) | hi) ^ sw) << 3;
      bf16x8 k0 = *reinterpret_cast<const bf16x8*>(Kb + l31 * 128 + so);
      bf16x8 k1 = *reinterpret_cast<const bf16x8*>(Kb + (32 + l31) * 128 + so);
      st0 = __builtin_amdgcn_mfma_f32_32x32x16_bf16(k0, qf[ks], st0, 0, 0, 0);
      st1 = __builtin_amdgcn_mfma_f32_32x32x16_bf16(k1, qf[ks], st1, 0, 0, 0);
    }
    __builtin_amdgcn_s_setprio(0);
  };
  auto pv = [&](int vb) {
    const bf16_t* Vb = VsB + vb * 6144;
    __builtin_amdgcn_s_setprio(1);
#pragma unroll
    for (int ks2 = 0; ks2 < 4; ++ks2) {
      const int so = (((ks2 << 1) | hi) ^ sw) << 3;
      bf16x8 v0 = *reinterpret_cast<const bf16x8*>(Vb + l31 * 64 + so);
      bf16x8 v1 = *reinterpret_cast<const bf16x8*>(Vb + (32 + l31) * 64 + so);
      bf16x8 v2 = *reinterpret_cast<const bf16x8*>(Vb + (64 + l31) * 64 + so);
      o0 = __builtin_amdgcn_mfma_f32_32x32x16_bf16(v0, pb[ks2], o0, 0, 0, 0);
      o1 = __builtin_amdgcn_mfma_f32_32x32x16_bf16(v1, pb[ks2], o1, 0, 0, 0);
      o2 = __builtin_amdgcn_mfma_f32_32x32x16_bf16(v2, pb[ks2], o2, 0, 0, 0);
    }
    __builtin_amdgcn_s_setprio(0);
  };
  auto softmax_pack = [&]() {
    float mt[16];
#pragma unroll
    for (int r = 0; r < 16; ++r) mt[r] = fmaxf(st0[r], st1[r]);
#pragma unroll
    for (int s2 = 8; s2 >= 1; s2 >>= 1)
#pragma unroll
      for (int r = 0; r < s2; ++r) mt[r] = fmaxf(mt[r], mt[r + s2]);
    float mx = fmaxf(mt[0], __shfl_xor(mt[0], 32));
    if (!__all(mx <= mrun + 6.0f)) {           // THR=6 (base-2): P bounded by 64
      float mnew = fmaxf(mrun, mx);
      float corr = __builtin_exp2f(mrun - mnew);
      mrun = mnew;
#pragma unroll
      for (int r = 0; r < 16; ++r) { o0[r] *= corr; o1[r] *= corr; o2[r] *= corr; }
    }
#pragma unroll
    for (int r = 0; r < 16; ++r) st0[r] = __builtin_exp2f(st0[r] - mrun);
#pragma unroll
    for (int r = 0; r < 16; ++r) st1[r] = __builtin_exp2f(st1[r] - mrun);
#pragma unroll
    for (int u = 0; u < 2; ++u)
#pragma unroll
      for (int j = 0; j < 8; ++j) {
        pb[u][j]     = (bf16_t)st0[u * 8 + j];
        pb[2 + u][j] = (bf16_t)st1[u * 8 + j];
      }
  };

  // prologue: tile 0 staged; QK(0)+SM(0) packed, PV deferred one tile
  issue(0);
  commit(0, 0);
  __syncthreads();
  issue(64);
  qk(0);
  softmax_pack();
  commit(1, 1);
  __syncthreads();

#pragma unroll 1
  for (int t = 1; t < 16; ++t) {
    if (t < 15) issue((t + 1) * 64);
    qk(t & 1);                                 // S(t): MFMA pipe
    pv((t - 1) % 3);                           // PV(t-1): MFMA pipe, indep of st
    softmax_pack();                            // SM(t): VALU, overlaps PV MFMAs
    if (t < 15) commit((t + 1) & 1, (t + 1) % 3);
    __syncthreads();
  }
  pv(0);                                       // PV(15), Vbuf 15%3 == 0
  __syncthreads();                             // V reads done before Osm overwrites

  // ---- normalize: sum(P) is o2 reg 8 (row 80) on hi=0 lanes; hi=1 holds 0 ----
  float sp = o2[8] + __shfl_xor(o2[8], 32);
  float inv = 1.0f / sp;

  bf16_t* Osm = (bf16_t*)smem;  // [256][88]
  const int qrow = w * 32 + l31;
#pragma unroll
  for (int r = 0; r < 16; ++r) {
    int crow = (r & 3) + 8 * (r >> 2) + 4 * hi;
    Osm[qrow * 88 + crow]      = (bf16_t)(o0[r] * inv);
    Osm[qrow * 88 + 32 + crow] = (bf16_t)(o1[r] * inv);
    if (r < 8) Osm[qrow * 88 + 64 + crow] = (bf16_t)(o2[r] * inv);
  }
  __syncthreads();
#pragma unroll
  for (int i = 0; i < 5; ++i) {
    int c = tid + i * 512;
    int q = c / 10, ch = c - q * 10;
    uint4 v = *reinterpret_cast<const uint4*>(Osm + q * 88 + ch * 8);
    *reinterpret_cast<uint4*>(outp + (size_t)(q0 + q) * DIM + h * 80 + ch * 8) = v;
  }
}

// ---------------- launch ----------------
extern "C" void kernel_launch(void* const* d_in, const int* in_sizes, int n_in,
                              void* d_out, int out_size, void* d_ws, size_t ws_size,
                              hipStream_t stream) {
  const float* hs    = (const float*)d_in[0];
  const float* cosT  = (const float*)d_in[1];
  const float* sinT  = (const float*)d_in[2];
  const float* Wqkv  = (const float*)d_in[3];
  const float* bqkv  = (const float*)d_in[4];
  const float* Wproj = (const float*)d_in[5];
  const float* bproj = (const float*)d_in[6];
  (void)in_sizes; (void)n_in; (void)out_size; (void)ws_size;

  char* ws = (char*)d_ws;
  bf16_t* hsb  = (bf16_t*)(ws);                    // 20,971,520 B (reused as vtg after GEMM)
  bf16_t* w1t  = (bf16_t*)(ws + 20971520);         //  9,830,400
  bf16_t* w2t  = (bf16_t*)(ws + 30801920);         //  3,276,800
  bf16_t* qkvb = (bf16_t*)(ws + 34078720);         // 62,914,560
  bf16_t* attn = (bf16_t*)(ws + 96993280);         // 20,971,520
  bf16_t* vtg  = hsb;

  k_conv_bf16<<<5120, 256, 0, stream>>>(hs, hsb);
  k_transpose_bf16<<<dim3(120, 40), dim3(32, 8), 0, stream>>>(Wqkv, w1t, 1280, 3840);
  k_transpose_bf16<<<dim3(40, 40), dim3(32, 8), 0, stream>>>(Wproj, w2t, 1280, 1280);
  k_gemm8<true, true><<<480, 512, 0, stream>>>(hsb, w1t, bqkv, (void*)qkvb, 3840, cosT, sinT);
  k_vtrans<<<2048, 256, 0, stream>>>(qkvb, vtg);
  k_attn2<<<512, 512, 0, stream>>>(qkvb, vtg, attn);
  k_gemm8<false, false><<<160, 512, 0, stream>>>(attn, w2t, bproj, d_out, 1280, nullptr, nullptr);
}

// Round 20
// 233.305 us; speedup vs baseline: 1.3285x; 1.3285x over previous
//
#include <hip/hip_runtime.h>
#include <hip/hip_bf16.h>
#include <stdint.h>

typedef __bf16 bf16_t;
typedef __bf16 bf16x8 __attribute__((ext_vector_type(8)));
typedef float f32x4 __attribute__((ext_vector_type(4)));
typedef float f32x16 __attribute__((ext_vector_type(16)));

#define S_TOK 8192
#define DIM   1280
#define NH    16
#define HD    80
#define LSEQ  1024
#define N_QKV 3840

// q/k columns are stored PAIR-INTERLEAVED per head: col j (even) = orig d=j/2,
// col j (odd) = orig d=j/2+40. QK^T is invariant (q,k share the permutation);
// V region (n>=2560) is identity. qk_perm maps stored col -> original col.
__device__ __forceinline__ int qk_perm(int n) {
  if (n >= 2560) return n;
  int base = (n / 80) * 80, j = n - base;
  return base + ((j & 1) ? (j >> 1) + 40 : (j >> 1));
}

// async global->LDS, 16B per lane; lds dest is wave-uniform base + lane*16
__device__ __forceinline__ void gload16(const bf16_t* g, void* l) {
  __builtin_amdgcn_global_load_lds(
      (__attribute__((address_space(1))) uint32_t*)g,
      (__attribute__((address_space(3))) uint32_t*)l, 16, 0, 0);
}

// ---------------- fp32 -> bf16 convert (hidden_states) ----------------
__global__ __launch_bounds__(256) void k_conv_bf16(const float* __restrict__ in,
                                                   bf16_t* __restrict__ out) {
  int g = blockIdx.x * 256 + threadIdx.x;
  const float4* p = reinterpret_cast<const float4*>(in) + (size_t)g * 2;
  float4 v0 = p[0], v1 = p[1];
  bf16x8 o;
  o[0] = (bf16_t)v0.x; o[1] = (bf16_t)v0.y; o[2] = (bf16_t)v0.z; o[3] = (bf16_t)v0.w;
  o[4] = (bf16_t)v1.x; o[5] = (bf16_t)v1.y; o[6] = (bf16_t)v1.z; o[7] = (bf16_t)v1.w;
  *reinterpret_cast<bf16x8*>(out + (size_t)g * 8) = o;
}

// ---------------- W [K][N] fp32 -> Wt [N][K] bf16 ----------------
__global__ __launch_bounds__(256) void k_transpose_bf16(const float* __restrict__ W,
                                                        bf16_t* __restrict__ Wt,
                                                        int K, int N) {
  __shared__ float tile[32][33];
  int n0 = blockIdx.x * 32, k0 = blockIdx.y * 32;
  int tx = threadIdx.x, ty = threadIdx.y;
#pragma unroll
  for (int j = 0; j < 32; j += 8)
    tile[ty + j][tx] = W[(size_t)(k0 + ty + j) * N + n0 + tx];
  __syncthreads();
#pragma unroll
  for (int j = 0; j < 32; j += 8)
    Wt[(size_t)(n0 + ty + j) * K + k0 + tx] = (bf16_t)tile[tx][ty + j];
}

// ---------------- GEMM v8 (round-18 exact): 256x256, BK=64, 2-phase + fused RoPE ----------------
template <bool OUT_BF16, bool ROPE>
__global__ __launch_bounds__(512, 2) void k_gemm8(const bf16_t* __restrict__ A,
                                                  const bf16_t* __restrict__ Bt,
                                                  const float* __restrict__ bias,
                                                  void* __restrict__ Cout,
                                                  int N,
                                                  const float* __restrict__ cosT,
                                                  const float* __restrict__ sinT) {
  constexpr int K = 1280;
  constexpr int NT = K / 64;                     // 20 K-tiles
  const float QS = 0.11180339887498949f * 1.4426950408889634f;
  __shared__ __align__(16) char smem[131072];    // [2][A 32KB | B 32KB]
  const int nb = N >> 8;
  const int cpx = (int)gridDim.x >> 3;           // grid % 8 == 0
  const int wg = ((int)blockIdx.x & 7) * cpx + ((int)blockIdx.x >> 3);
  const int bm = wg / nb, bn = wg % nb;
  const int tid = threadIdx.x, lane = tid & 63, w = tid >> 6;
  const int wm = w >> 2, wn = w & 3;             // 2 x 4 wave grid
  const int l15 = lane & 15, lg = lane >> 4;

  const bf16_t* Ab = A + (size_t)(bm * 256) * K;

  const int srow = w * 8 + (lane >> 3);
  const int scol = ((lane & 7) ^ (lane >> 3)) * 8;   // inverse-swizzled source chunk

  int srowB[4];
#pragma unroll
  for (int g = 0; g < 4; ++g) {
    int n = bn * 256 + g * 64 + srow;
    srowB[g] = ROPE ? qk_perm(n) : n;
  }

  float bv4[4];
#pragma unroll
  for (int nf = 0; nf < 4; ++nf) {
    int col = bn * 256 + wn * 64 + nf * 16 + l15;
    bv4[nf] = bias[ROPE ? qk_perm(col) : col];
  }
  asm volatile("" :: "v"(bv4[0]), "v"(bv4[1]), "v"(bv4[2]), "v"(bv4[3]) : "memory");

  char* const sm = smem;
  auto stageA = [&](int buf, int g, int k0) {
    gload16(Ab + (size_t)(g * 64 + srow) * K + k0 + scol,
            sm + buf * 65536 + g * 8192 + w * 1024);
  };
  auto stageB = [&](int buf, int g, int k0) {
    gload16(Bt + (size_t)srowB[g] * K + k0 + scol,
            sm + buf * 65536 + 32768 + g * 8192 + w * 1024);
  };

  f32x4 acc[8][4];
#pragma unroll
  for (int i = 0; i < 8; ++i)
#pragma unroll
    for (int j = 0; j < 4; ++j) acc[i][j] = (f32x4){0.f, 0.f, 0.f, 0.f};

#pragma unroll
  for (int g = 0; g < 4; ++g) { stageA(0, g, 0); stageB(0, g, 0); }
  asm volatile("s_waitcnt vmcnt(0)\n\ts_barrier" ::: "memory");

#pragma unroll 1
  for (int T = 0; T < NT; ++T) {
    const int buf = T & 1, nbuf = buf ^ 1;
    const int k1 = (T + 1) * 64;
    if (T + 1 < NT) {
#pragma unroll
      for (int g = 0; g < 4; ++g) { stageA(nbuf, g, k1); stageB(nbuf, g, k1); }
    }
    const char* Abase = sm + buf * 65536;
    const char* Bbase = Abase + 32768;
#pragma unroll
    for (int kk = 0; kk < 2; ++kk) {
      const int cb = kk * 64 + lg * 16;
      bf16x8 bfv[4];
#pragma unroll
      for (int nf = 0; nf < 4; ++nf) {
        const int row = wn * 64 + nf * 16 + l15;
        bfv[nf] = *reinterpret_cast<const bf16x8*>(Bbase + row * 128 + (cb ^ ((row & 7) << 4)));
      }
#pragma unroll
      for (int mg = 0; mg < 2; ++mg) {
        bf16x8 af[4];
#pragma unroll
        for (int mf = 0; mf < 4; ++mf) {
          const int row = wm * 128 + mg * 64 + mf * 16 + l15;
          af[mf] = *reinterpret_cast<const bf16x8*>(Abase + row * 128 + (cb ^ ((row & 7) << 4)));
        }
        __builtin_amdgcn_s_setprio(1);
#pragma unroll
        for (int mf = 0; mf < 4; ++mf)
#pragma unroll
          for (int nf = 0; nf < 4; ++nf)
            acc[mg * 4 + mf][nf] =
                __builtin_amdgcn_mfma_f32_16x16x32_bf16(af[mf], bfv[nf], acc[mg * 4 + mf][nf], 0, 0, 0);
        __builtin_amdgcn_s_setprio(0);
      }
    }
    if (T + 1 < NT) {
      asm volatile("s_waitcnt vmcnt(0)\n\ts_barrier" ::: "memory");
    }
  }

  const int rg = lg << 2;

  if constexpr (ROPE) {
    // stage cos/sin [256 rows][40 pi] into dead LDS (coalesced), round-18 form
    float* ldsC = reinterpret_cast<float*>(sm);            // [256][44] padded
    float* ldsS = reinterpret_cast<float*>(sm + 45056);    // [256][44]
    __syncthreads();
#pragma unroll
    for (int i = 0; i < 5; ++i) {
      int c = tid + i * 512;
      int row = c / 10, q4 = c - row * 10;
      float4 vc = *reinterpret_cast<const float4*>(cosT + (size_t)(bm * 256 + row) * 80 + q4 * 4);
      float4 vs = *reinterpret_cast<const float4*>(sinT + (size_t)(bm * 256 + row) * 80 + q4 * 4);
      *reinterpret_cast<float4*>(ldsC + row * 44 + q4 * 4) = vc;
      *reinterpret_cast<float4*>(ldsS + row * 44 + q4 * 4) = vs;
    }
    __syncthreads();

#pragma unroll
    for (int nf = 0; nf < 4; ++nf) {
      const int col = bn * 256 + wn * 64 + nf * 16 + l15;
      const float bv = bv4[nf];
      const bool isqk = col < 2560;
      const bool isq  = col < 1280;
      const int pi = (col % 80) >> 1;
      const float sgn = (l15 & 1) ? 1.f : -1.f;
#pragma unroll
      for (int m8 = 0; m8 < 8; ++m8) {
        const int row0 = bm * 256 + wm * 128 + m8 * 16 + rg;
        const int lrow0 = wm * 128 + m8 * 16 + rg;
#pragma unroll
        for (int r = 0; r < 4; ++r) {
          float v = acc[m8][nf][r] + bv;
          if (isqk) {
            float other = __shfl_xor(v, 1);
            float c = ldsC[(lrow0 + r) * 44 + pi];
            float s = ldsS[(lrow0 + r) * 44 + pi];
            v = v * c + sgn * other * s;
            if (isq) v *= QS;
          }
          reinterpret_cast<bf16_t*>(Cout)[(size_t)(row0 + r) * N + col] = (bf16_t)v;
        }
      }
    }
  } else {
#pragma unroll
    for (int nf = 0; nf < 4; ++nf) {
      const int col = bn * 256 + wn * 64 + nf * 16 + l15;
      const float bv = bv4[nf];
#pragma unroll
      for (int m8 = 0; m8 < 8; ++m8) {
        const int row0 = bm * 256 + wm * 128 + m8 * 16 + rg;
#pragma unroll
        for (int r = 0; r < 4; ++r) {
          float v = acc[m8][nf][r] + bv;
          if (OUT_BF16)
            reinterpret_cast<bf16_t*>(Cout)[(size_t)(row0 + r) * N + col] = (bf16_t)v;
          else
            reinterpret_cast<float*>(Cout)[(size_t)(row0 + r) * N + col] = v;
        }
      }
    }
  }
}

// ---------------- V transpose+permute: vtg[seg][h][d][kv'] = V[seg][swap23(kv')][h][d] ----------------
__global__ __launch_bounds__(256) void k_vtrans(const bf16_t* __restrict__ qkv,
                                                bf16_t* __restrict__ vtg) {
  __shared__ bf16_t T[64][88];
  int sh = blockIdx.x >> 4;            // seg*16 + h
  int kt = blockIdx.x & 15;
  int seg = sh >> 4, h = sh & 15;
  int kv0 = kt * 64;
  int tid = threadIdx.x;
#pragma unroll
  for (int i = 0; i < 3; ++i) {
    int c = tid + i * 256;
    if (c < 640) {
      int r = c / 10, ch = c - r * 10;
      *reinterpret_cast<uint4*>(&T[r][ch * 8]) =
        *reinterpret_cast<const uint4*>(qkv + (size_t)(seg * 1024 + kv0 + r) * N_QKV + 2 * DIM + h * 80 + ch * 8);
    }
  }
  __syncthreads();
#pragma unroll
  for (int i = 0; i < 3; ++i) {
    int c = tid + i * 256;
    if (c < 640) {
      int d = c >> 3, co = c & 7;
      bf16x8 o;
#pragma unroll
      for (int j = 0; j < 8; ++j) {
        int kp = co * 8 + j;
        int kv = (kp & ~12) | (((kp >> 2) & 1) << 3) | (((kp >> 3) & 1) << 2);  // swap bits 2,3
        o[j] = T[kv][d];
      }
      *reinterpret_cast<bf16x8*>(vtg + ((size_t)(sh * 80 + d)) * 1024 + kv0 + co * 8) = o;
    }
  }
}

// ---------------- V pad rows: vpad[0][*]=1.0 (sum row), vpad[1..15][*]=0 ----------------
__global__ __launch_bounds__(256) void k_padinit(bf16_t* __restrict__ vpad) {
  int g = blockIdx.x * 256 + threadIdx.x;        // 2048 x uint4 = 32 KB
  const uint4 ones4 = {0x3F803F80u, 0x3F803F80u, 0x3F803F80u, 0x3F803F80u};
  const uint4 z4 = {0u, 0u, 0u, 0u};
  reinterpret_cast<uint4*>(vpad)[g] = (g < 128) ? ones4 : z4;
}

// ---------------- flash attention v8: lagged-PV + global_load_lds staging ----------------
// Staging rewritten per rule #21: LINEAR gload_lds dest (wave-uniform + lane*16)
// + inverse-XOR-swizzled per-lane GLOBAL source; read side byte-identical to v7
// (slot s of row r holds chunk s^(r&7)). V pad rows (d>=80: ones row for the
// sum-via-MFMA trick, zeros) stream from vpad. __syncthreads drains vmcnt(0)
// (compiler-tracked gload_lds) -> race-free with the same buffer rotation.
__global__ __launch_bounds__(512, 2) void k_attn2(const bf16_t* __restrict__ qkv,
                                                  const bf16_t* __restrict__ vtg,
                                                  const bf16_t* __restrict__ vpad,
                                                  bf16_t* __restrict__ outp) {
  __shared__ __align__(16) char smem[69632];
  // K: 2 x 16384 B at offset 0 ([64][128] bf16); V: 3 x 12288 B at 32768 ([96][64])

  const int bid = blockIdx.x;
  const int seg = bid & 7, qt = (bid >> 3) & 3, h = bid >> 5;
  const int tid = threadIdx.x, lane = tid & 63, w = tid >> 6;
  const int l31 = lane & 31, hi = lane >> 5;
  const int sw = l31 & 7;                      // row-XOR key (rows l31+32k share it)
  const int q0 = seg * 1024 + qt * 256;

  const bf16_t* kbase = qkv + ((size_t)seg * 1024) * N_QKV + DIM + h * 80;
  const bf16_t* vbase = vtg + ((size_t)(seg * 16 + h) * 80) * 1024;

  bf16x8 qf[5];
  {
    const bf16_t* qp = qkv + (size_t)(q0 + w * 32 + l31) * N_QKV + h * 80 + hi * 8;
#pragma unroll
    for (int ks = 0; ks < 5; ++ks) qf[ks] = *reinterpret_cast<const bf16x8*>(qp + ks * 16);
  }

  // ---- staging geometry (per-lane global sources, fixed; advance per tile) ----
  // K: 16 x 1KB segments; wave w owns s in {2w, 2w+1}; lane -> row 4s+(l>>4),
  // slot l&15; source chunk = slot ^ (row&7)  (inverse of the read-side XOR).
  const int kr0 = 8 * w + (lane >> 4);            // row of segment 2w
  const int kr1 = kr0 + 4;                        // row of segment 2w+1
  const bf16_t* kSrc0 = kbase + (size_t)kr0 * N_QKV + (((lane & 15) ^ (kr0 & 7)) << 3);
  const bf16_t* kSrc1 = kbase + (size_t)kr1 * N_QKV + (((lane & 15) ^ (kr1 & 7)) << 3);
  const int kDst0 = 2 * w * 1024, kDst1 = kDst0 + 1024;  // byte offsets in K buf
  // V: 12 x 1KB segments; wave w owns s=w, and s=8+w for w<4; lane -> row
  // d=8s+(l>>3), slot l&7; source chunk = slot ^ (d&7) = (l&7)^(l>>3).
  const int vcofs = (((lane & 7) ^ (lane >> 3)) << 3);    // element offset
  const int vd0 = 8 * w + (lane >> 3);                    // d < 64 always
  const bf16_t* vSrc0 = vbase + (size_t)vd0 * 1024 + vcofs;
  const int vDst0 = w * 1024;
  const bf16_t* vSrc1 = nullptr;
  int vDst1 = 0;
  if (w < 4) {
    const int d1 = 64 + 8 * w + (lane >> 3);              // 64..95
    vSrc1 = (d1 < 80) ? (vbase + (size_t)d1 * 1024 + vcofs)
                      : (vpad + (size_t)(d1 - 80) * 1024 + vcofs);
    vDst1 = (8 + w) * 1024;
  }

  auto gstage = [&](int kv0, int kb, int vb) {
    char* Kb = smem + kb * 16384;
    char* Vb = smem + 32768 + vb * 12288;
    const size_t kadv = (size_t)kv0 * N_QKV;
    gload16(kSrc0 + kadv, Kb + kDst0);
    gload16(kSrc1 + kadv, Kb + kDst1);
    gload16(vSrc0 + kv0, Vb + vDst0);
    if (w < 4) gload16(vSrc1 + kv0, Vb + vDst1);
  };

  f32x16 o0, o1, o2;
#pragma unroll
  for (int r = 0; r < 16; ++r) { o0[r] = 0.f; o1[r] = 0.f; o2[r] = 0.f; }
  float mrun = -1e30f;
  f32x16 st0, st1;
  bf16x8 pb[4];

  auto qk = [&](int kb) {
#pragma unroll
    for (int r = 0; r < 16; ++r) { st0[r] = 0.f; st1[r] = 0.f; }
    const bf16_t* Kb = (const bf16_t*)(smem + kb * 16384);
    __builtin_amdgcn_s_setprio(1);
#pragma unroll
    for (int ks = 0; ks < 5; ++ks) {
      const int so = (((ks << 1) | hi) ^ sw) << 3;
      bf16x8 k0 = *reinterpret_cast<const bf16x8*>(Kb + l31 * 128 + so);
      bf16x8 k1 = *reinterpret_cast<const bf16x8*>(Kb + (32 + l31) * 128 + so);
      st0 = __builtin_amdgcn_mfma_f32_32x32x16_bf16(k0, qf[ks], st0, 0, 0, 0);
      st1 = __builtin_amdgcn_mfma_f32_32x32x16_bf16(k1, qf[ks], st1, 0, 0, 0);
    }
    __builtin_amdgcn_s_setprio(0);
  };
  auto pv = [&](int vb) {
    const bf16_t* Vb = (const bf16_t*)(smem + 32768 + vb * 12288);
    __builtin_amdgcn_s_setprio(1);
#pragma unroll
    for (int ks2 = 0; ks2 < 4; ++ks2) {
      const int so = (((ks2 << 1) | hi) ^ sw) << 3;
      bf16x8 v0 = *reinterpret_cast<const bf16x8*>(Vb + l31 * 64 + so);
      bf16x8 v1 = *reinterpret_cast<const bf16x8*>(Vb + (32 + l31) * 64 + so);
      bf16x8 v2 = *reinterpret_cast<const bf16x8*>(Vb + (64 + l31) * 64 + so);
      o0 = __builtin_amdgcn_mfma_f32_32x32x16_bf16(v0, pb[ks2], o0, 0, 0, 0);
      o1 = __builtin_amdgcn_mfma_f32_32x32x16_bf16(v1, pb[ks2], o1, 0, 0, 0);
      o2 = __builtin_amdgcn_mfma_f32_32x32x16_bf16(v2, pb[ks2], o2, 0, 0, 0);
    }
    __builtin_amdgcn_s_setprio(0);
  };
  auto softmax_pack = [&]() {
    float mt[16];
#pragma unroll
    for (int r = 0; r < 16; ++r) mt[r] = fmaxf(st0[r], st1[r]);
#pragma unroll
    for (int s2 = 8; s2 >= 1; s2 >>= 1)
#pragma unroll
      for (int r = 0; r < s2; ++r) mt[r] = fmaxf(mt[r], mt[r + s2]);
    float mx = fmaxf(mt[0], __shfl_xor(mt[0], 32));
    if (!__all(mx <= mrun + 6.0f)) {           // THR=6 (base-2): P bounded by 64
      float mnew = fmaxf(mrun, mx);
      float corr = __builtin_exp2f(mrun - mnew);
      mrun = mnew;
#pragma unroll
      for (int r = 0; r < 16; ++r) { o0[r] *= corr; o1[r] *= corr; o2[r] *= corr; }
    }
#pragma unroll
    for (int r = 0; r < 16; ++r) st0[r] = __builtin_exp2f(st0[r] - mrun);
#pragma unroll
    for (int r = 0; r < 16; ++r) st1[r] = __builtin_exp2f(st1[r] - mrun);
#pragma unroll
    for (int u = 0; u < 2; ++u)
#pragma unroll
      for (int j = 0; j < 8; ++j) {
        pb[u][j]     = (bf16_t)st0[u * 8 + j];
        pb[2 + u][j] = (bf16_t)st1[u * 8 + j];
      }
  };

  // prologue: stage tile 0 -> (K0,V0); drain; stage tile 1 under QK(0)+SM(0)
  gstage(0, 0, 0);
  __syncthreads();                               // vmcnt(0) drain (compiler)
  gstage(64, 1, 1);
  qk(0);
  softmax_pack();
  __syncthreads();                               // tile-1 loads landed

#pragma unroll 1
  for (int t = 1; t < 16; ++t) {
    if (t < 15) gstage((t + 1) * 64, (t + 1) & 1, (t + 1) % 3);
    qk(t & 1);                                 // S(t): MFMA pipe
    pv((t - 1) % 3);                           // PV(t-1): MFMA pipe, indep of st
    softmax_pack();                            // SM(t): VALU, overlaps PV MFMAs
    __syncthreads();                           // t+1 loads landed; buffers sealed
  }
  pv(0);                                       // PV(15), Vbuf 15%3 == 0
  __syncthreads();                             // V reads done before Osm overwrites

  // ---- normalize: sum(P) is o2 reg 8 (row 80 = ones) on hi=0 lanes ----
  float sp = o2[8] + __shfl_xor(o2[8], 32);
  float inv = 1.0f / sp;

  bf16_t* Osm = (bf16_t*)smem;  // [256][88]
  const int qrow = w * 32 + l31;
#pragma unroll
  for (int r = 0; r < 16; ++r) {
    int crow = (r & 3) + 8 * (r >> 2) + 4 * hi;
    Osm[qrow * 88 + crow]      = (bf16_t)(o0[r] * inv);
    Osm[qrow * 88 + 32 + crow] = (bf16_t)(o1[r] * inv);
    if (r < 8) Osm[qrow * 88 + 64 + crow] = (bf16_t)(o2[r] * inv);
  }
  __syncthreads();
#pragma unroll
  for (int i = 0; i < 5; ++i) {
    int c = tid + i * 512;
    int q = c / 10, ch = c - q * 10;
    uint4 v = *reinterpret_cast<const uint4*>(Osm + q * 88 + ch * 8);
    *reinterpret_cast<uint4*>(outp + (size_t)(q0 + q) * DIM + h * 80 + ch * 8) = v;
  }
}

// ---------------- launch ----------------
extern "C" void kernel_launch(void* const* d_in, const int* in_sizes, int n_in,
                              void* d_out, int out_size, void* d_ws, size_t ws_size,
                              hipStream_t stream) {
  const float* hs    = (const float*)d_in[0];
  const float* cosT  = (const float*)d_in[1];
  const float* sinT  = (const float*)d_in[2];
  const float* Wqkv  = (const float*)d_in[3];
  const float* bqkv  = (const float*)d_in[4];
  const float* Wproj = (const float*)d_in[5];
  const float* bproj = (const float*)d_in[6];
  (void)in_sizes; (void)n_in; (void)out_size; (void)ws_size;

  char* ws = (char*)d_ws;
  bf16_t* hsb  = (bf16_t*)(ws);                    // 20,971,520 B (reused as vtg after GEMM)
  bf16_t* w1t  = (bf16_t*)(ws + 20971520);         //  9,830,400  (dead after QKV GEMM)
  bf16_t* w2t  = (bf16_t*)(ws + 30801920);         //  3,276,800
  bf16_t* qkvb = (bf16_t*)(ws + 34078720);         // 62,914,560
  bf16_t* attn = (bf16_t*)(ws + 96993280);         // 20,971,520
  bf16_t* vtg  = hsb;
  bf16_t* vpad = w1t;                              // 32 KB carved from dead w1t

  k_conv_bf16<<<5120, 256, 0, stream>>>(hs, hsb);
  k_transpose_bf16<<<dim3(120, 40), dim3(32, 8), 0, stream>>>(Wqkv, w1t, 1280, 3840);
  k_transpose_bf16<<<dim3(40, 40), dim3(32, 8), 0, stream>>>(Wproj, w2t, 1280, 1280);
  k_gemm8<true, true><<<480, 512, 0, stream>>>(hsb, w1t, bqkv, (void*)qkvb, 3840, cosT, sinT);
  k_padinit<<<8, 256, 0, stream>>>(vpad);          // after QKV GEMM (w1t now dead)
  k_vtrans<<<2048, 256, 0, stream>>>(qkvb, vtg);
  k_attn2<<<512, 512, 0, stream>>>(qkvb, vtg, vpad, attn);
  k_gemm8<false, false><<<160, 512, 0, stream>>>(attn, w2t, bproj, d_out, 1280, nullptr, nullptr);
}